// Round 2
// baseline (350.602 us; speedup 1.0000x reference)
//
#include <hip/hip_runtime.h>

#define RPB 256          // rows per block == threads per block
#define RSTRIDE 17       // LDS row stride in words: 16 + 1 pad -> <=2-way banks both phases

__global__ __launch_bounds__(256) void rinter_area_kernel(
    const float* __restrict__ int_pts,
    const int* __restrict__ num_of_inter,
    float* __restrict__ out,
    int n)
{
    __shared__ float s[RPB * RSTRIDE];   // 17 KB

    const int t = threadIdx.x;
    const int row0 = blockIdx.x * RPB;

    // Phase 1: fully coalesced float4 loads of the block's 256 rows (16 KB),
    // scattered into LDS. Row stride 17 words: store banks (17r+4j+c)%32 and
    // load banks (17t+m)%32 are both exactly 2-way aliased across a wave (free).
    const float4* src = (const float4*)(int_pts + (size_t)row0 * 16);
    #pragma unroll
    for (int k = 0; k < 4; ++k) {
        int g = t + k * RPB;          // float4 index within block chunk, 0..1023
        int r = g >> 2;               // local row
        int j = g & 3;                // float4 slot within row
        if (row0 + r < n) {
            float4 v = src[g];
            float* d = s + r * RSTRIDE + j * 4;
            d[0] = v.x; d[1] = v.y; d[2] = v.z; d[3] = v.w;
        }
    }
    __syncthreads();

    const int i = row0 + t;
    if (i >= n) return;

    // Phase 2: each thread reads its own row from LDS (scalar ds_read_b32,
    // 2-way = conflict-free), all indices compile-time constant -> registers.
    const float* p = s + t * RSTRIDE;
    const float p1x = p[0], p1y = p[1];
    const int nt = num_of_inter[i] - 2;   // triangles: j < nt, nt in [-2, 6]

    float acc = 0.0f;
    #pragma unroll
    for (int j = 0; j < 6; ++j) {
        float p2x = p[2 + 2 * j], p2y = p[3 + 2 * j];
        float p3x = p[4 + 2 * j], p3y = p[5 + 2 * j];
        float cross = (p1x - p3x) * (p2y - p3y) - (p1y - p3y) * (p2x - p3x);
        acc += (j < nt) ? fabsf(cross) * 0.5f : 0.0f;
    }
    out[i] = acc;
}

extern "C" void kernel_launch(void* const* d_in, const int* in_sizes, int n_in,
                              void* d_out, int out_size, void* d_ws, size_t ws_size,
                              hipStream_t stream) {
    const float* int_pts      = (const float*)d_in[0];
    const int*   num_of_inter = (const int*)d_in[1];
    float*       out          = (float*)d_out;
    const int n = in_sizes[1];  // one num_of_inter entry per row

    const int block = 256;
    const int grid = (n + block - 1) / block;
    rinter_area_kernel<<<grid, block, 0, stream>>>(int_pts, num_of_inter, out, n);
}